// Round 16
// baseline (404.227 us; speedup 1.0000x reference)
//
#include <hip/hip_runtime.h>

typedef unsigned short u16;
typedef unsigned int u32;
typedef unsigned long long u64;

typedef float f32x4 __attribute__((ext_vector_type(4)));
typedef short bf16x8 __attribute__((ext_vector_type(8)));

#define BB 8
#define NQ 1024
#define NK 256
#define HH 8
#define KD 544   // padded score-dot length (11*48=528 -> 544 = 17*32)

__device__ __forceinline__ float bf2f(u16 u) {
  union { u32 i; float f; } v; v.i = ((u32)u) << 16; return v.f;
}
__device__ __forceinline__ u16 f2bf(float f) {
  union { u32 i; float f; } v; v.f = f;
  u32 i = v.i;
  return (u16)((i + 0x7FFFu + ((i >> 16) & 1u)) >> 16);
}
__device__ __forceinline__ float softplusf(float d) {
  return (d > 20.f) ? d : log1pf(__expf(d));
}

// grade per component c (GRADE_IDX), nibble-packed
#define GRADE_TAB 0x4333322222211110ULL
// active component for score-slot s (slots 0..10 = INNER(8) then POINT(3))
#define ACT_TAB   0xDCBEA984320ULL
__device__ __forceinline__ int grade_of(int c) { return (int)((GRADE_TAB >> (c * 4)) & 15ULL); }
__device__ __forceinline__ int act_of(int s) { return (int)((ACT_TAB >> (s * 4)) & 15ULL); }

constexpr float INV_S384 = 0.05103103630798288f; // 1/sqrt(8*48)

// ---------------------------------------------------------------------------
// wB_kernel: WqB[g][o][64] / WkvB[g][o][64] bf16 (K padded 48->64, zeros) for
// MFMA B-frags; WoB = bf16(Wo).  Also zeroes kbias (accumulated atomically by
// qkv_mfma point tasks).
// ---------------------------------------------------------------------------
__global__ __launch_bounds__(256) void wB_kernel(
    const float* __restrict__ Wq, const float* __restrict__ Wkv,
    const float* __restrict__ Wo, u16* __restrict__ WqB,
    u16* __restrict__ WkvB, u16* __restrict__ WoB,
    float* __restrict__ kbias) {
  int idx = blockIdx.x * 256 + threadIdx.x;
  const int NA = 5 * 384 * 64, NB = 5 * 768 * 64, NC = 5 * 48 * 384;
  if (idx < BB * HH * NK) kbias[idx] = 0.f;
  if (idx < NA) {
    int g = idx / (384 * 64);
    int rem = idx - g * 384 * 64;
    int o = rem >> 6, j = rem & 63;
    WqB[idx] = (j < 48) ? f2bf(Wq[((size_t)g * 384 + o) * 48 + j]) : (u16)0;
  } else if (idx < NA + NB) {
    int k = idx - NA;
    int g = k / (768 * 64);
    int rem = k - g * 768 * 64;
    int o = rem >> 6, j = rem & 63;
    WkvB[k] = (j < 48) ? f2bf(Wkv[((size_t)g * 768 + o) * 48 + j]) : (u16)0;
  } else if (idx < NA + NB + NC) {
    int k = idx - NA - NB;
    WoB[k] = f2bf(Wo[k]);
  }
}

// ---------------------------------------------------------------------------
// xJ_kernel (merged hidden+vis, rms fused): bid<128 -> hidden (norm), else
// vis.  x[row][i*16+c] (f32) -> dst[c][row][64] bf16 (48 real + 16 zero pad).
// ---------------------------------------------------------------------------
__global__ __launch_bounds__(256) void xJ_kernel(
    const float* __restrict__ hidden, const float* __restrict__ vis,
    u16* __restrict__ xq, u16* __restrict__ xv,
    const float* __restrict__ lnw) {
  __shared__ __align__(16) float ls[16 * 772];
  __shared__ float rs_s[16];
  const int t = threadIdx.x;
  const int bid = blockIdx.x;
  const float* src;
  u16* dst;
  int NR, norm, row0;
  if (bid < 128) { src = hidden; dst = xq; NR = 8192; norm = 1; row0 = bid * 64; }
  else           { src = vis;    dst = xv; NR = 2048; norm = 0; row0 = (bid - 128) * 64; }
  const int row16 = t & 15, c = t >> 4;
  for (int chunk = 0; chunk < 4; chunk++) {
    const int r0c = row0 + chunk * 16;
    __syncthreads();
#pragma unroll
    for (int k = 0; k < 12; k++) {
      int f = t + 256 * k;
      int r = f / 192, j = f - r * 192;
      *(float4*)&ls[r * 772 + j * 4] =
          *(const float4*)(src + (size_t)(r0c + r) * 768 + j * 4);
    }
    __syncthreads();
    if (norm) {
      const int r = t >> 4, j16 = t & 15;
      float s = 0.f;
#pragma unroll
      for (int i = 0; i < 12; i++) {
        float4 v = *(const float4*)&ls[r * 772 + j16 * 48 + i * 4];
        s += v.x * v.x + v.y * v.y + v.z * v.z + v.w * v.w;
      }
#pragma unroll
      for (int off = 8; off; off >>= 1) s += __shfl_xor(s, off, 16);
      if (j16 == 0) rs_s[r] = rsqrtf(s * (1.f / 48.f) + 1e-6f);
      __syncthreads();
    }
    const float rsv = norm ? rs_s[row16] : 1.f;
    u16 buf[64];
#pragma unroll
    for (int i = 0; i < 48; i++) {
      float v = ls[row16 * 772 + i * 16 + c];
      if (norm) v *= rsv * lnw[i];
      buf[i] = f2bf(v);
    }
#pragma unroll
    for (int i = 48; i < 64; i++) buf[i] = 0;
    u16* dp = dst + ((size_t)c * NR + r0c + row16) * 64;
#pragma unroll
    for (int j4 = 0; j4 < 8; j4++) *(uint4*)(dp + j4 * 8) = *(uint4*)&buf[j4 * 8];
  }
}

// ---------------------------------------------------------------------------
// qkv_mfma (merged q_mfma + kv_mfma + k2-fold): 1D grid 2272.
//  bid < 1408: q path (rowblk = bid&127, slot = bid>>7).
//  else: kv path (kvid = bid-1408; keyblk = kvid&31, task = kvid>>5);
//    point tasks (8..10) also atomicAdd raw k^2 sums into kbias (scale
//    applied in attn).  Shared 55.3KB LDS buffer covers both paths.
// ---------------------------------------------------------------------------
#define QSTR 392
#define VSTR 72
__global__ __launch_bounds__(256) void qkv_mfma(
    const u16* __restrict__ xq, const u16* __restrict__ xv,
    const u16* __restrict__ WqB, const u16* __restrict__ WkvB,
    const float* __restrict__ bq, const float* __restrict__ bkv,
    const float* __restrict__ daa, u16* __restrict__ qsel,
    u16* __restrict__ ksel, u16* __restrict__ vT,
    float* __restrict__ kbias) {
  __shared__ __align__(16) u16 es[384 * VSTR];  // 55.3 KB (max of both paths)
  const int t = threadIdx.x;
  const int w = t >> 6, lane = t & 63, m16 = lane & 15, quad = lane >> 4;
  const int bid = blockIdx.x;

  if (bid < 1408) {
    // ---------------- q path ----------------
    const int rowblk = bid & 127, slot = bid >> 7;
    const int c = act_of(slot), g = grade_of(c);
    const int row0 = rowblk * 64;
    const int b = row0 >> 10, n0 = row0 & 1023;
    f32x4 acc[24];
#pragma unroll
    for (int nt = 0; nt < 24; nt++) acc[nt] = (f32x4)0.f;
    const u16* ap = xq + ((size_t)c * 8192 + row0 + w * 16 + m16) * 64 + quad * 8;
    const u16* wb = WqB + (size_t)g * 384 * 64 + (size_t)m16 * 64 + quad * 8;
#pragma unroll
    for (int ks = 0; ks < 2; ks++) {
      bf16x8 af = *(const bf16x8*)(ap + ks * 32);
#pragma unroll
      for (int nt = 0; nt < 24; nt++) {
        bf16x8 bf = *(const bf16x8*)(wb + (size_t)nt * 16 * 64 + ks * 32);
        acc[nt] = __builtin_amdgcn_mfma_f32_16x16x32_bf16(af, bf, acc[nt], 0, 0, 0);
      }
    }
#pragma unroll
    for (int nt = 0; nt < 24; nt++) {
      const int o = nt * 16 + m16;
      const int h = o / 48;
      const float sc = (slot < 8) ? INV_S384 : (2.f * softplusf(daa[h]) * (1.f / 48.f));
      const float bias = (slot == 0) ? bq[o] : 0.f;
#pragma unroll
      for (int rr = 0; rr < 4; rr++)
        es[(w * 16 + quad * 4 + rr) * QSTR + o] = f2bf((acc[nt][rr] + bias) * sc);
    }
    __syncthreads();
    for (int ch = t; ch < 512; ch += 256) {
      int r = ch >> 3, h = ch & 7;
      const uint4* sr = (const uint4*)&es[r * QSTR + h * 48];
      u16* dst = qsel + ((size_t)(b * 8 + h) * NQ + n0 + r) * KD + slot * 48;
#pragma unroll
      for (int j = 0; j < 6; j++) ((uint4*)dst)[j] = sr[j];
      if (slot == 10) {
        uint4 z = {0u, 0u, 0u, 0u};
        ((uint4*)dst)[6] = z;  // [528,536)
        ((uint4*)dst)[7] = z;  // [536,544)
      }
    }
    return;
  }

  // ---------------- kv path ----------------
  const int kvid = bid - 1408;
  const int keyblk = kvid & 31, task = kvid >> 5;
  const int row0 = keyblk * 64;
  const int b = row0 >> 8, n0 = row0 & 255;

  if (task < 11) {
    const int c = act_of(task), g = grade_of(c);
    f32x4 acc[24];
#pragma unroll
    for (int nt = 0; nt < 24; nt++) acc[nt] = (f32x4)0.f;
    const u16* ap = xv + ((size_t)c * 2048 + row0 + w * 16 + m16) * 64 + quad * 8;
    const u16* wb = WkvB + (size_t)g * 768 * 64 + (size_t)m16 * 64 + quad * 8;
#pragma unroll
    for (int ks = 0; ks < 2; ks++) {
      bf16x8 af = *(const bf16x8*)(ap + ks * 32);
#pragma unroll
      for (int nt = 0; nt < 24; nt++) {
        bf16x8 bf = *(const bf16x8*)(wb + (size_t)nt * 16 * 64 + ks * 32);
        acc[nt] = __builtin_amdgcn_mfma_f32_16x16x32_bf16(af, bf, acc[nt], 0, 0, 0);
      }
    }
#pragma unroll
    for (int nt = 0; nt < 24; nt++) {
      const int o = nt * 16 + m16;
      const float bias = (task == 0) ? bkv[o] : 0.f;
#pragma unroll
      for (int rr = 0; rr < 4; rr++)
        es[(w * 16 + quad * 4 + rr) * QSTR + o] = f2bf(acc[nt][rr] + bias);
    }
    __syncthreads();
    for (int ch = t; ch < 512; ch += 256) {
      int r = ch >> 3, h = ch & 7;
      const uint4* sr = (const uint4*)&es[r * QSTR + h * 48];
      u16* dst = ksel + ((size_t)(b * 8 + h) * NK + n0 + r) * KD + task * 48;
#pragma unroll
      for (int j = 0; j < 6; j++) ((uint4*)dst)[j] = sr[j];
      if (task == 10) {
        uint4 z = {0u, 0u, 0u, 0u};
        ((uint4*)dst)[6] = z;
        ((uint4*)dst)[7] = z;
      }
    }
    // k2-fold: point slots accumulate raw sum(k^2) per (key,h) via atomics
    if (task >= 8) {
      for (int id = t; id < 512; id += 256) {
        int r = id >> 3, hh = id & 7;
        const u16* er = &es[r * QSTR + hh * 48];
        float s = 0.f;
#pragma unroll
        for (int oc = 0; oc < 48; oc++) { float v = bf2f(er[oc]); s += v * v; }
        atomicAdd(&kbias[((size_t)(b * 8 + hh)) * NK + n0 + r], s);
      }
    }
  } else {
    const int c = task - 11, g = grade_of(c);
    f32x4 acc[24];
#pragma unroll
    for (int nt = 0; nt < 24; nt++) acc[nt] = (f32x4)0.f;
    const u16* ap = xv + ((size_t)c * 2048 + row0 + w * 16 + m16) * 64 + quad * 8;
    const u16* wb = WkvB + (size_t)g * 768 * 64 + (size_t)(384 + m16) * 64 + quad * 8;
#pragma unroll
    for (int ks = 0; ks < 2; ks++) {
      bf16x8 af = *(const bf16x8*)(ap + ks * 32);
#pragma unroll
      for (int nt = 0; nt < 24; nt++) {
        bf16x8 bf = *(const bf16x8*)(wb + (size_t)nt * 16 * 64 + ks * 32);
        acc[nt] = __builtin_amdgcn_mfma_f32_16x16x32_bf16(af, bf, acc[nt], 0, 0, 0);
      }
    }
#pragma unroll
    for (int nt = 0; nt < 24; nt++) {
      const int o = nt * 16 + m16;
      const float bias = (c == 0) ? bkv[384 + o] : 0.f;
#pragma unroll
      for (int rr = 0; rr < 4; rr++)
        es[o * VSTR + w * 16 + quad * 4 + rr] = f2bf(acc[nt][rr] + bias);
    }
    __syncthreads();
    for (int id = t; id < 6144; id += 256) {
      int o = id >> 4, part = id & 15;
      uint2 v = *(const uint2*)&es[o * VSTR + part * 4];
      int h = o / 48, oc = o - h * 48;
      *(uint2*)(vT + ((size_t)(b * 8 + h) * 768 + oc * 16 + c) * 256 + n0 + part * 4) = v;
    }
  }
}

// ---------------------------------------------------------------------------
// MFMA attention v16 = v15 + 3 blocks/CU (enabled by read-affinity):
//  * v15 proved FETCH 227->71MB via h=XCD affinity -> attn is now latency-
//    bound, not traffic-bound -> re-open the occupancy lever.  v9's thrash
//    at 3 blocks was WITHOUT affinity (24 scattered K/V groups); with
//    affinity only ~6 groups/XCD ~ 4MB.
//  * LDS diet: epilogue in 4 chunks of 4 c (stg 53.2->26.6KB; union = spb
//    34.3KB), padded to 50.2KB so total = 53.2KB -> exactly 3 blocks/CU.
//    STGW stays 26 (v9's stride-25 bank-conflict mistake avoided).
// ---------------------------------------------------------------------------
#define SPBW 268
#define STGW 26
#define UNIW 12544   // u32; 50.2KB pad -> total LDS 53.2KB -> 3 blocks/CU

#define QK_MFMA_BLOCK(AQ0, AQ1, AQ2, AQ3, AK0, AK1, AK2, AK3)                 \
  sacc[0][0] = __builtin_amdgcn_mfma_f32_16x16x32_bf16(AQ0, AK0, sacc[0][0], 0, 0, 0); \
  sacc[1][0] = __builtin_amdgcn_mfma_f32_16x16x32_bf16(AQ1, AK0, sacc[1][0], 0, 0, 0); \
  sacc[2][0] = __builtin_amdgcn_mfma_f32_16x16x32_bf16(AQ2, AK0, sacc[2][0], 0, 0, 0); \
  sacc[3][0] = __builtin_amdgcn_mfma_f32_16x16x32_bf16(AQ3, AK0, sacc[3][0], 0, 0, 0); \
  sacc[0][1] = __builtin_amdgcn_mfma_f32_16x16x32_bf16(AQ0, AK1, sacc[0][1], 0, 0, 0); \
  sacc[1][1] = __builtin_amdgcn_mfma_f32_16x16x32_bf16(AQ1, AK1, sacc[1][1], 0, 0, 0); \
  sacc[2][1] = __builtin_amdgcn_mfma_f32_16x16x32_bf16(AQ2, AK1, sacc[2][1], 0, 0, 0); \
  sacc[3][1] = __builtin_amdgcn_mfma_f32_16x16x32_bf16(AQ3, AK1, sacc[3][1], 0, 0, 0); \
  sacc[0][2] = __builtin_amdgcn_mfma_f32_16x16x32_bf16(AQ0, AK2, sacc[0][2], 0, 0, 0); \
  sacc[1][2] = __builtin_amdgcn_mfma_f32_16x16x32_bf16(AQ1, AK2, sacc[1][2], 0, 0, 0); \
  sacc[2][2] = __builtin_amdgcn_mfma_f32_16x16x32_bf16(AQ2, AK2, sacc[2][2], 0, 0, 0); \
  sacc[3][2] = __builtin_amdgcn_mfma_f32_16x16x32_bf16(AQ3, AK2, sacc[3][2], 0, 0, 0); \
  sacc[0][3] = __builtin_amdgcn_mfma_f32_16x16x32_bf16(AQ0, AK3, sacc[0][3], 0, 0, 0); \
  sacc[1][3] = __builtin_amdgcn_mfma_f32_16x16x32_bf16(AQ1, AK3, sacc[1][3], 0, 0, 0); \
  sacc[2][3] = __builtin_amdgcn_mfma_f32_16x16x32_bf16(AQ2, AK3, sacc[2][3], 0, 0, 0); \
  sacc[3][3] = __builtin_amdgcn_mfma_f32_16x16x32_bf16(AQ3, AK3, sacc[3][3], 0, 0, 0);

__global__ __launch_bounds__(256, 2) void attn_kernel(
    const u16* __restrict__ qsel, const u16* __restrict__ ksel,
    const float* __restrict__ kbias, const float* __restrict__ daa,
    const u16* __restrict__ vT, u16* __restrict__ ctxJ) {
  // XCD read-affinity decode: h = XCD, qt innermost within (b,h)
  const int bid = blockIdx.x;
  const int h = bid & 7;
  const int qt = (bid >> 3) & 15;
  const int b = bid >> 7;
  const int g = b * 8 + h;

  const int t = threadIdx.x;
  const int w = t >> 6;
  const int lane = t & 63;
  const int m16 = lane & 15;
  const int quad = lane >> 4;

  // union: P (bf16, 64x268 = 34.3KB) / staging (26.6KB); padded for 3/CU
  __shared__ __align__(16) u32 uni_s[UNIW];
  u16* spb = (u16*)uni_s;
  u32* stg = uni_s;
  __shared__ float kb[256];
  __shared__ __align__(16) float wred[64][4];
  __shared__ __align__(16) float wsum[64][4];

  const size_t bh = (size_t)g;
  const int n0 = qt * 64;
  const u16* qg = qsel + (bh * NQ + n0) * KD;
  const u16* kg = ksel + bh * NK * KD;
  const u16* vg = vT + bh * 768 * 256;

  const float ksc = -(softplusf(daa[h]) * (1.f / 48.f));
  kb[t] = ksc * kbias[bh * NK + t];
  __syncthreads();
  float kbr[4];
#pragma unroll
  for (int nt = 0; nt < 4; nt++) kbr[nt] = kb[w * 64 + nt * 16 + m16];

  f32x4 sacc[4][4];
#pragma unroll
  for (int mt = 0; mt < 4; mt++)
#pragma unroll
    for (int nt = 0; nt < 4; nt++) sacc[mt][nt] = (f32x4)0.f;

  // ---- QK^T: 17 K-steps, 2-deep software pipeline ----
  const u16* qp0 = qg + (size_t)m16 * KD + quad * 8;
  const u16* qp1 = qg + (size_t)(16 + m16) * KD + quad * 8;
  const u16* qp2 = qg + (size_t)(32 + m16) * KD + quad * 8;
  const u16* qp3 = qg + (size_t)(48 + m16) * KD + quad * 8;
  const u16* kp = kg + (size_t)(w * 64 + m16) * KD + quad * 8;
  bf16x8 cq0 = *(const bf16x8*)qp0;
  bf16x8 cq1 = *(const bf16x8*)qp1;
  bf16x8 cq2 = *(const bf16x8*)qp2;
  bf16x8 cq3 = *(const bf16x8*)qp3;
  bf16x8 ck0 = *(const bf16x8*)(kp);
  bf16x8 ck1 = *(const bf16x8*)(kp + 16 * KD);
  bf16x8 ck2 = *(const bf16x8*)(kp + 32 * KD);
  bf16x8 ck3 = *(const bf16x8*)(kp + 48 * KD);
  bf16x8 dq0 = *(const bf16x8*)(qp0 + 32);
  bf16x8 dq1 = *(const bf16x8*)(qp1 + 32);
  bf16x8 dq2 = *(const bf16x8*)(qp2 + 32);
  bf16x8 dq3 = *(const bf16x8*)(qp3 + 32);
  bf16x8 dk0 = *(const bf16x8*)(kp + 32);
  bf16x8 dk1 = *(const bf16x8*)(kp + 16 * KD + 32);
  bf16x8 dk2 = *(const bf16x8*)(kp + 32 * KD + 32);
  bf16x8 dk3 = *(const bf16x8*)(kp + 48 * KD + 32);
  for (int i = 0; i < 7; i++) {
    const int oA = (2 * i + 2) * 32;
    bf16x8 nq0 = *(const bf16x8*)(qp0 + oA);
    bf16x8 nq1 = *(const bf16x8*)(qp1 + oA);
    bf16x8 nq2 = *(const bf16x8*)(qp2 + oA);
    bf16x8 nq3 = *(const bf16x8*)(qp3 + oA);
    bf16x8 nk0 = *(const bf16x8*)(kp + oA);
    bf16x8 nk1 = *(const bf16x8*)(kp + 16 * KD + oA);
    bf16x8 nk2 = *(const bf16x8*)(kp + 32 * KD + oA);
    bf16x8 nk3 = *(const bf16x8*)(kp + 48 * KD + oA);
    const int oB = (2 * i + 3) * 32;
    bf16x8 mq0 = *(const bf16x8*)(qp0 + oB);
    bf16x8 mq1 = *(const bf16x8*)(qp1 + oB);
    bf16x8 mq2 = *(const bf16x8*)(qp2 + oB);
    bf16x8 mq3 = *(const bf16x8*)(qp3 + oB);
    bf16x8 mk0 = *(const bf16x8*)(kp + oB);
    bf16x8 mk1 = *(const bf16x8*)(kp + 16 * KD + oB);
    bf16x8 mk2 = *(const bf16x8*)(kp + 32 * KD + oB);
    bf16x8 mk3 = *(const bf16x8*)(kp + 48 * KD + oB);
    QK_MFMA_BLOCK(cq0, cq1, cq2, cq3, ck0, ck1, ck2, ck3)
    QK_MFMA_BLOCK(dq0, dq1, dq2, dq3, dk0, dk1, dk2, dk3)
    cq0 = nq0; cq1 = nq1; cq2 = nq2; cq3 = nq3;
    ck0 = nk0; ck1 = nk1; ck2 = nk2; ck3 = nk3;
    dq0 = mq0; dq1 = mq1; dq2 = mq2; dq3 = mq3;
    dk0 = mk0; dk1 = mk1; dk2 = mk2; dk3 = mk3;
  }
  {
    const int oT = 16 * 32;
    bf16x8 nq0 = *(const bf16x8*)(qp0 + oT);
    bf16x8 nq1 = *(const bf16x8*)(qp1 + oT);
    bf16x8 nq2 = *(const bf16x8*)(qp2 + oT);
    bf16x8 nq3 = *(const bf16x8*)(qp3 + oT);
    bf16x8 nk0 = *(const bf16x8*)(kp + oT);
    bf16x8 nk1 = *(const bf16x8*)(kp + 16 * KD + oT);
    bf16x8 nk2 = *(const bf16x8*)(kp + 32 * KD + oT);
    bf16x8 nk3 = *(const bf16x8*)(kp + 48 * KD + oT);
    QK_MFMA_BLOCK(cq0, cq1, cq2, cq3, ck0, ck1, ck2, ck3)
    QK_MFMA_BLOCK(dq0, dq1, dq2, dq3, dk0, dk1, dk2, dk3)
    QK_MFMA_BLOCK(nq0, nq1, nq2, nq3, nk0, nk1, nk2, nk3)
  }

  // ---- softmax, in-register ----
#pragma unroll
  for (int mt = 0; mt < 4; mt++)
#pragma unroll
    for (int rr = 0; rr < 4; rr++) {
      float a0 = sacc[mt][0][rr] + kbr[0];
      float a1 = sacc[mt][1][rr] + kbr[1];
      float a2 = sacc[mt][2][rr] + kbr[2];
      float a3 = sacc[mt][3][rr] + kbr[3];
      sacc[mt][0][rr] = a0; sacc[mt][1][rr] = a1;
      sacc[mt][2][rr] = a2; sacc[mt][3][rr] = a3;
      float m = fmaxf(fmaxf(a0, a1), fmaxf(a2, a3));
#pragma unroll
      for (int off = 1; off < 16; off <<= 1)
        m = fmaxf(m, __shfl_xor(m, off));
      if (m16 == mt * 4 + rr) wred[mt * 16 + quad * 4 + rr][w] = m;
    }
  __syncthreads();
#pragma unroll
  for (int mt = 0; mt < 4; mt++)
#pragma unroll
    for (int rr = 0; rr < 4; rr++) {
      const int row = mt * 16 + quad * 4 + rr;
      float4 m4 = *(const float4*)wred[row];
      const float gm = fmaxf(fmaxf(m4.x, m4.y), fmaxf(m4.z, m4.w));
      float s = 0.f;
#pragma unroll
      for (int nt = 0; nt < 4; nt++) {
        float e = __expf(sacc[mt][nt][rr] - gm);
        s += e;
        spb[row * SPBW + w * 64 + nt * 16 + m16] = f2bf(e);
      }
#pragma unroll
      for (int off = 1; off < 16; off <<= 1)
        s += __shfl_xor(s, off);
      if (m16 == mt * 4 + rr) wsum[row][w] = s;
    }
  __syncthreads();

  // ---- PV: D[m=q-row][n=d]; 1-deep V prefetch ----
  f32x4 oacc[4][12];
#pragma unroll
  for (int mt = 0; mt < 4; mt++)
#pragma unroll
    for (int nt = 0; nt < 12; nt++) oacc[mt][nt] = (f32x4)0.f;

  const u16* vp = vg + (size_t)(w * 192 + m16) * 256 + quad * 8;
  bf16x8 vc[12];
#pragma unroll
  for (int nt = 0; nt < 12; nt++)
    vc[nt] = *(const bf16x8*)(vp + (size_t)nt * 16 * 256);
#pragma unroll
  for (int ks = 0; ks < 8; ks++) {
    bf16x8 vn[12];
    if (ks < 7) {
#pragma unroll
      for (int nt = 0; nt < 12; nt++)
        vn[nt] = *(const bf16x8*)(vp + (size_t)nt * 16 * 256 + (ks + 1) * 32);
    }
    bf16x8 pa0 = *(const bf16x8*)(&spb[(size_t)m16 * SPBW + ks * 32 + quad * 8]);
    bf16x8 pa1 = *(const bf16x8*)(&spb[(size_t)(16 + m16) * SPBW + ks * 32 + quad * 8]);
    bf16x8 pa2 = *(const bf16x8*)(&spb[(size_t)(32 + m16) * SPBW + ks * 32 + quad * 8]);
    bf16x8 pa3 = *(const bf16x8*)(&spb[(size_t)(48 + m16) * SPBW + ks * 32 + quad * 8]);
#pragma unroll
    for (int nt = 0; nt < 12; nt++) {
      oacc[0][nt] = __builtin_amdgcn_mfma_f32_16x16x32_bf16(pa0, vc[nt], oacc[0][nt], 0, 0, 0);
      oacc[1][nt] = __builtin_amdgcn_mfma_f32_16x16x32_bf16(pa1, vc[nt], oacc[1][nt], 0, 0, 0);
      oacc[2][nt] = __builtin_amdgcn_mfma_f32_16x16x32_bf16(pa2, vc[nt], oacc[2][nt], 0, 0, 0);
      oacc[3][nt] = __builtin_amdgcn_mfma_f32_16x16x32_bf16(pa3, vc[nt], oacc[3][nt], 0, 0, 0);
    }
    if (ks < 7) {
#pragma unroll
      for (int nt = 0; nt < 12; nt++) vc[nt] = vn[nt];
    }
  }

  // ---- staged epilogue: 4 chunks of 4 c; full 96B runs, h-OUTER ctxJ ----
  const size_t rowbase = (size_t)b * NQ + n0;
#pragma unroll
  for (int ch2 = 0; ch2 < 4; ch2++) {
    __syncthreads();
    if ((m16 >> 2) == ch2) {
      const int c4 = m16 & 3;
#pragma unroll
      for (int mt = 0; mt < 4; mt++)
#pragma unroll
        for (int rr = 0; rr < 4; rr++) {
          const int row = mt * 16 + quad * 4 + rr;
          float4 s4 = *(const float4*)wsum[row];
          const float iv = 1.f / (s4.x + s4.y + s4.z + s4.w);
          u32* dp = stg + (row * 4 + c4) * STGW + w * 6;
#pragma unroll
          for (int j = 0; j < 6; j++) {
            u32 lo = f2bf(oacc[mt][2 * j][rr] * iv);
            u32 hi = f2bf(oacc[mt][2 * j + 1][rr] * iv);
            dp[j] = lo | (hi << 16);
          }
        }
    }
    __syncthreads();
    // 256 runs, one per thread: row = t>>2, c4 = t&3
    {
      const int prow = t >> 2, pc4 = t & 3;
      const u32* sp2 = stg + (prow * 4 + pc4) * STGW;
      u16* dst = ctxJ +
          (((size_t)(h * 16 + ch2 * 4 + pc4)) * 8192 + rowbase + prow) * 48;
#pragma unroll
      for (int j6 = 0; j6 < 6; j6++) {
        uint2 a = *(const uint2*)(sp2 + j6 * 4);
        uint2 bb2 = *(const uint2*)(sp2 + j6 * 4 + 2);
        uint4 v4v = {a.x, a.y, bb2.x, bb2.y};
        *(uint4*)(dst + j6 * 8) = v4v;
      }
    }
  }
}

// ---------------------------------------------------------------------------
// out_kernel v6: 16 rows/block, grid 512, 2 blocks/CU.  ctxJ h-outer
// [h*16+c][row][48] -> per-fragment decode h=k/48 (48%8==0 so each 8-elem
// fragment stays inside one h-slice; harness-verified).
// ---------------------------------------------------------------------------
#define ESTR2 785
__global__ __launch_bounds__(1024) void out_kernel(
    const u16* __restrict__ ctxJ, const u16* __restrict__ WoB,
    const float* __restrict__ bo, const float* __restrict__ hidden,
    float* __restrict__ out) {
  __shared__ __align__(16) float es[16 * ESTR2];  // 50.2 KB
  const int t = threadIdx.x;
  const int c = __builtin_amdgcn_readfirstlane(t >> 6);
  const int lane = t & 63;
  const int m16 = lane & 15, quad = lane >> 4;
  const int r0 = blockIdx.x * 16;
  const int g = grade_of(c);
  const u16* wb = WoB + (size_t)g * 48 * 384;
  const int q8 = quad * 8;

  f32x4 acc[3];
#pragma unroll
  for (int nt = 0; nt < 3; nt++) acc[nt] = (f32x4)0.f;
#pragma unroll
  for (int ks = 0; ks < 12; ks++) {
    const int k0 = ks * 32 + q8;
    const int hh = k0 / 48;
    const int oc = k0 - hh * 48;
    bf16x8 af = *(const bf16x8*)(ctxJ +
        (((size_t)(hh * 16 + c)) * 8192 + r0 + m16) * 48 + oc);
#pragma unroll
    for (int nt = 0; nt < 3; nt++) {
      bf16x8 bf = *(const bf16x8*)(wb + (size_t)(nt * 16 + m16) * 384 + ks * 32 + q8);
      acc[nt] = __builtin_amdgcn_mfma_f32_16x16x32_bf16(af, bf, acc[nt], 0, 0, 0);
    }
  }
  __syncthreads();
#pragma unroll
  for (int nt = 0; nt < 3; nt++)
#pragma unroll
    for (int rr = 0; rr < 4; rr++)
      es[(quad * 4 + rr) * ESTR2 + c * 49 + nt * 16 + m16] = acc[nt][rr];
  __syncthreads();
#pragma unroll
  for (int k = 0; k < 3; k++) {
    int m4 = t + 1024 * k;
    int r = m4 / 192;
    int col0 = (m4 - r * 192) * 4;
    int o = col0 >> 4, cb = col0 & 15;
    const float* er = &es[r * ESTR2 + o];
    float4 v;
    v.x = er[(cb + 0) * 49];
    v.y = er[(cb + 1) * 49];
    v.z = er[(cb + 2) * 49];
    v.w = er[(cb + 3) * 49];
    if (cb == 0) v.x += bo[o];
    size_t gidx = (size_t)(r0 + r) * 768 + col0;
    const float4 hv = *(const float4*)&hidden[gidx];
    v.x += hv.x; v.y += hv.y; v.z += hv.z; v.w += hv.w;
    *(float4*)&out[gidx] = v;
  }
}

// ---------------------------------------------------------------------------
extern "C" void kernel_launch(void* const* d_in, const int* in_sizes, int n_in,
                              void* d_out, int out_size, void* d_ws, size_t ws_size,
                              hipStream_t stream) {
  const float* hidden = (const float*)d_in[0];
  const float* vis = (const float*)d_in[1];
  const float* lnw = (const float*)d_in[2];
  const float* Wq = (const float*)d_in[3];
  const float* bq = (const float*)d_in[4];
  const float* Wkv = (const float*)d_in[5];
  const float* bkv = (const float*)d_in[6];
  const float* Wo = (const float*)d_in[7];
  const float* bo = (const float*)d_in[8];
  const float* daa = (const float*)d_in[9];
  float* out = (float*)d_out;

  char* ws = (char*)d_ws;
  size_t off = 0;
  auto carve = [&](size_t bytes) -> void* {
    void* p = ws + off;
    off += (bytes + 255) & ~(size_t)255;
    return p;
  };
  u16* WqB = (u16*)carve((size_t)5 * 384 * 64 * 2);
  u16* WkvB = (u16*)carve((size_t)5 * 768 * 64 * 2);
  u16* WoB = (u16*)carve((size_t)5 * 48 * 384 * 2);
  u16* qsel = (u16*)carve((size_t)BB * HH * NQ * KD * 2);
  u16* ksel = (u16*)carve((size_t)BB * HH * NK * KD * 2);
  u16* vT = (u16*)carve((size_t)BB * HH * 768 * 256 * 2);
  float* kbias = (float*)carve((size_t)BB * HH * NK * 4);
  // union: [xq | xv] consumed by qkv, then ctxJ ([h*16+c][row][48]) overwrites
  char* uni = (char*)carve((size_t)16 * 384 * 8192 * 2);
  u16* ctxJ = (u16*)uni;
  u16* xq = (u16*)uni;                                      // 16 MB
  u16* xv = (u16*)(uni + (size_t)16 * 8192 * 64 * 2);       // 4 MB

  wB_kernel<<<1800, 256, 0, stream>>>(Wq, Wkv, Wo, WqB, WkvB, WoB, kbias);
  xJ_kernel<<<160, 256, 0, stream>>>(hidden, vis, xq, xv, lnw);
  qkv_mfma<<<2272, 256, 0, stream>>>(xq, xv, WqB, WkvB, bq, bkv, daa,
                                     qsel, ksel, vT, kbias);
  attn_kernel<<<1024, 256, 0, stream>>>(qsel, ksel, kbias, daa, vT, ctxJ);
  out_kernel<<<512, 1024, 0, stream>>>(ctxJ, WoB, bo, hidden, out);
}

// Round 17
// 390.534 us; speedup vs baseline: 1.0351x; 1.0351x over previous
//
#include <hip/hip_runtime.h>

typedef unsigned short u16;
typedef unsigned int u32;
typedef unsigned long long u64;

typedef float f32x4 __attribute__((ext_vector_type(4)));
typedef short bf16x8 __attribute__((ext_vector_type(8)));

#define BB 8
#define NQ 1024
#define NK 256
#define HH 8
#define KD 544   // padded score-dot length (11*48=528 -> 544 = 17*32)

__device__ __forceinline__ float bf2f(u16 u) {
  union { u32 i; float f; } v; v.i = ((u32)u) << 16; return v.f;
}
__device__ __forceinline__ u16 f2bf(float f) {
  union { u32 i; float f; } v; v.f = f;
  u32 i = v.i;
  return (u16)((i + 0x7FFFu + ((i >> 16) & 1u)) >> 16);
}
__device__ __forceinline__ float softplusf(float d) {
  return (d > 20.f) ? d : log1pf(__expf(d));
}

// grade per component c (GRADE_IDX), nibble-packed
#define GRADE_TAB 0x4333322222211110ULL
// active component for score-slot s (slots 0..10 = INNER(8) then POINT(3))
#define ACT_TAB   0xDCBEA984320ULL
__device__ __forceinline__ int grade_of(int c) { return (int)((GRADE_TAB >> (c * 4)) & 15ULL); }
__device__ __forceinline__ int act_of(int s) { return (int)((ACT_TAB >> (s * 4)) & 15ULL); }

constexpr float INV_S384 = 0.05103103630798288f; // 1/sqrt(8*48)

// ---------------------------------------------------------------------------
// wB_kernel: WqB[g][o][64] / WkvB[g][o][64] bf16 (K padded 48->64, zeros) for
// MFMA B-frags; WoB = bf16(Wo).  Also zeroes kbias (accumulated atomically by
// qkv_mfma point tasks).
// ---------------------------------------------------------------------------
__global__ __launch_bounds__(256) void wB_kernel(
    const float* __restrict__ Wq, const float* __restrict__ Wkv,
    const float* __restrict__ Wo, u16* __restrict__ WqB,
    u16* __restrict__ WkvB, u16* __restrict__ WoB,
    float* __restrict__ kbias) {
  int idx = blockIdx.x * 256 + threadIdx.x;
  const int NA = 5 * 384 * 64, NB = 5 * 768 * 64, NC = 5 * 48 * 384;
  if (idx < BB * HH * NK) kbias[idx] = 0.f;
  if (idx < NA) {
    int g = idx / (384 * 64);
    int rem = idx - g * 384 * 64;
    int o = rem >> 6, j = rem & 63;
    WqB[idx] = (j < 48) ? f2bf(Wq[((size_t)g * 384 + o) * 48 + j]) : (u16)0;
  } else if (idx < NA + NB) {
    int k = idx - NA;
    int g = k / (768 * 64);
    int rem = k - g * 768 * 64;
    int o = rem >> 6, j = rem & 63;
    WkvB[k] = (j < 48) ? f2bf(Wkv[((size_t)g * 768 + o) * 48 + j]) : (u16)0;
  } else if (idx < NA + NB + NC) {
    int k = idx - NA - NB;
    WoB[k] = f2bf(Wo[k]);
  }
}

// ---------------------------------------------------------------------------
// xJ_kernel (merged hidden+vis, rms fused): bid<128 -> hidden (norm), else
// vis.  x[row][i*16+c] (f32) -> dst[c][row][64] bf16 (48 real + 16 zero pad).
// ---------------------------------------------------------------------------
__global__ __launch_bounds__(256) void xJ_kernel(
    const float* __restrict__ hidden, const float* __restrict__ vis,
    u16* __restrict__ xq, u16* __restrict__ xv,
    const float* __restrict__ lnw) {
  __shared__ __align__(16) float ls[16 * 772];
  __shared__ float rs_s[16];
  const int t = threadIdx.x;
  const int bid = blockIdx.x;
  const float* src;
  u16* dst;
  int NR, norm, row0;
  if (bid < 128) { src = hidden; dst = xq; NR = 8192; norm = 1; row0 = bid * 64; }
  else           { src = vis;    dst = xv; NR = 2048; norm = 0; row0 = (bid - 128) * 64; }
  const int row16 = t & 15, c = t >> 4;
  for (int chunk = 0; chunk < 4; chunk++) {
    const int r0c = row0 + chunk * 16;
    __syncthreads();
#pragma unroll
    for (int k = 0; k < 12; k++) {
      int f = t + 256 * k;
      int r = f / 192, j = f - r * 192;
      *(float4*)&ls[r * 772 + j * 4] =
          *(const float4*)(src + (size_t)(r0c + r) * 768 + j * 4);
    }
    __syncthreads();
    if (norm) {
      const int r = t >> 4, j16 = t & 15;
      float s = 0.f;
#pragma unroll
      for (int i = 0; i < 12; i++) {
        float4 v = *(const float4*)&ls[r * 772 + j16 * 48 + i * 4];
        s += v.x * v.x + v.y * v.y + v.z * v.z + v.w * v.w;
      }
#pragma unroll
      for (int off = 8; off; off >>= 1) s += __shfl_xor(s, off, 16);
      if (j16 == 0) rs_s[r] = rsqrtf(s * (1.f / 48.f) + 1e-6f);
      __syncthreads();
    }
    const float rsv = norm ? rs_s[row16] : 1.f;
    u16 buf[64];
#pragma unroll
    for (int i = 0; i < 48; i++) {
      float v = ls[row16 * 772 + i * 16 + c];
      if (norm) v *= rsv * lnw[i];
      buf[i] = f2bf(v);
    }
#pragma unroll
    for (int i = 48; i < 64; i++) buf[i] = 0;
    u16* dp = dst + ((size_t)c * NR + r0c + row16) * 64;
#pragma unroll
    for (int j4 = 0; j4 < 8; j4++) *(uint4*)(dp + j4 * 8) = *(uint4*)&buf[j4 * 8];
  }
}

// ---------------------------------------------------------------------------
// qkv_mfma (merged q_mfma + kv_mfma + k2-fold): 1D grid 2272.
//  bid < 1408: q path (rowblk = bid&127, slot = bid>>7).
//  else: kv path (kvid = bid-1408; keyblk = kvid&31, task = kvid>>5);
//    point tasks (8..10) also atomicAdd raw k^2 sums into kbias (scale
//    applied in attn).  Shared 55.3KB LDS buffer covers both paths.
// ---------------------------------------------------------------------------
#define QSTR 392
#define VSTR 72
__global__ __launch_bounds__(256) void qkv_mfma(
    const u16* __restrict__ xq, const u16* __restrict__ xv,
    const u16* __restrict__ WqB, const u16* __restrict__ WkvB,
    const float* __restrict__ bq, const float* __restrict__ bkv,
    const float* __restrict__ daa, u16* __restrict__ qsel,
    u16* __restrict__ ksel, u16* __restrict__ vT,
    float* __restrict__ kbias) {
  __shared__ __align__(16) u16 es[384 * VSTR];  // 55.3 KB (max of both paths)
  const int t = threadIdx.x;
  const int w = t >> 6, lane = t & 63, m16 = lane & 15, quad = lane >> 4;
  const int bid = blockIdx.x;

  if (bid < 1408) {
    // ---------------- q path ----------------
    const int rowblk = bid & 127, slot = bid >> 7;
    const int c = act_of(slot), g = grade_of(c);
    const int row0 = rowblk * 64;
    const int b = row0 >> 10, n0 = row0 & 1023;
    f32x4 acc[24];
#pragma unroll
    for (int nt = 0; nt < 24; nt++) acc[nt] = (f32x4)0.f;
    const u16* ap = xq + ((size_t)c * 8192 + row0 + w * 16 + m16) * 64 + quad * 8;
    const u16* wb = WqB + (size_t)g * 384 * 64 + (size_t)m16 * 64 + quad * 8;
#pragma unroll
    for (int ks = 0; ks < 2; ks++) {
      bf16x8 af = *(const bf16x8*)(ap + ks * 32);
#pragma unroll
      for (int nt = 0; nt < 24; nt++) {
        bf16x8 bf = *(const bf16x8*)(wb + (size_t)nt * 16 * 64 + ks * 32);
        acc[nt] = __builtin_amdgcn_mfma_f32_16x16x32_bf16(af, bf, acc[nt], 0, 0, 0);
      }
    }
#pragma unroll
    for (int nt = 0; nt < 24; nt++) {
      const int o = nt * 16 + m16;
      const int h = o / 48;
      const float sc = (slot < 8) ? INV_S384 : (2.f * softplusf(daa[h]) * (1.f / 48.f));
      const float bias = (slot == 0) ? bq[o] : 0.f;
#pragma unroll
      for (int rr = 0; rr < 4; rr++)
        es[(w * 16 + quad * 4 + rr) * QSTR + o] = f2bf((acc[nt][rr] + bias) * sc);
    }
    __syncthreads();
    for (int ch = t; ch < 512; ch += 256) {
      int r = ch >> 3, h = ch & 7;
      const uint4* sr = (const uint4*)&es[r * QSTR + h * 48];
      u16* dst = qsel + ((size_t)(b * 8 + h) * NQ + n0 + r) * KD + slot * 48;
#pragma unroll
      for (int j = 0; j < 6; j++) ((uint4*)dst)[j] = sr[j];
      if (slot == 10) {
        uint4 z = {0u, 0u, 0u, 0u};
        ((uint4*)dst)[6] = z;  // [528,536)
        ((uint4*)dst)[7] = z;  // [536,544)
      }
    }
    return;
  }

  // ---------------- kv path ----------------
  const int kvid = bid - 1408;
  const int keyblk = kvid & 31, task = kvid >> 5;
  const int row0 = keyblk * 64;
  const int b = row0 >> 8, n0 = row0 & 255;

  if (task < 11) {
    const int c = act_of(task), g = grade_of(c);
    f32x4 acc[24];
#pragma unroll
    for (int nt = 0; nt < 24; nt++) acc[nt] = (f32x4)0.f;
    const u16* ap = xv + ((size_t)c * 2048 + row0 + w * 16 + m16) * 64 + quad * 8;
    const u16* wb = WkvB + (size_t)g * 768 * 64 + (size_t)m16 * 64 + quad * 8;
#pragma unroll
    for (int ks = 0; ks < 2; ks++) {
      bf16x8 af = *(const bf16x8*)(ap + ks * 32);
#pragma unroll
      for (int nt = 0; nt < 24; nt++) {
        bf16x8 bf = *(const bf16x8*)(wb + (size_t)nt * 16 * 64 + ks * 32);
        acc[nt] = __builtin_amdgcn_mfma_f32_16x16x32_bf16(af, bf, acc[nt], 0, 0, 0);
      }
    }
#pragma unroll
    for (int nt = 0; nt < 24; nt++) {
      const int o = nt * 16 + m16;
      const float bias = (task == 0) ? bkv[o] : 0.f;
#pragma unroll
      for (int rr = 0; rr < 4; rr++)
        es[(w * 16 + quad * 4 + rr) * QSTR + o] = f2bf(acc[nt][rr] + bias);
    }
    __syncthreads();
    for (int ch = t; ch < 512; ch += 256) {
      int r = ch >> 3, h = ch & 7;
      const uint4* sr = (const uint4*)&es[r * QSTR + h * 48];
      u16* dst = ksel + ((size_t)(b * 8 + h) * NK + n0 + r) * KD + task * 48;
#pragma unroll
      for (int j = 0; j < 6; j++) ((uint4*)dst)[j] = sr[j];
      if (task == 10) {
        uint4 z = {0u, 0u, 0u, 0u};
        ((uint4*)dst)[6] = z;
        ((uint4*)dst)[7] = z;
      }
    }
    // k2-fold: point slots accumulate raw sum(k^2) per (key,h) via atomics
    if (task >= 8) {
      for (int id = t; id < 512; id += 256) {
        int r = id >> 3, hh = id & 7;
        const u16* er = &es[r * QSTR + hh * 48];
        float s = 0.f;
#pragma unroll
        for (int oc = 0; oc < 48; oc++) { float v = bf2f(er[oc]); s += v * v; }
        atomicAdd(&kbias[((size_t)(b * 8 + hh)) * NK + n0 + r], s);
      }
    }
  } else {
    const int c = task - 11, g = grade_of(c);
    f32x4 acc[24];
#pragma unroll
    for (int nt = 0; nt < 24; nt++) acc[nt] = (f32x4)0.f;
    const u16* ap = xv + ((size_t)c * 2048 + row0 + w * 16 + m16) * 64 + quad * 8;
    const u16* wb = WkvB + (size_t)g * 768 * 64 + (size_t)(384 + m16) * 64 + quad * 8;
#pragma unroll
    for (int ks = 0; ks < 2; ks++) {
      bf16x8 af = *(const bf16x8*)(ap + ks * 32);
#pragma unroll
      for (int nt = 0; nt < 24; nt++) {
        bf16x8 bf = *(const bf16x8*)(wb + (size_t)nt * 16 * 64 + ks * 32);
        acc[nt] = __builtin_amdgcn_mfma_f32_16x16x32_bf16(af, bf, acc[nt], 0, 0, 0);
      }
    }
#pragma unroll
    for (int nt = 0; nt < 24; nt++) {
      const int o = nt * 16 + m16;
      const float bias = (c == 0) ? bkv[384 + o] : 0.f;
#pragma unroll
      for (int rr = 0; rr < 4; rr++)
        es[o * VSTR + w * 16 + quad * 4 + rr] = f2bf(acc[nt][rr] + bias);
    }
    __syncthreads();
    for (int id = t; id < 6144; id += 256) {
      int o = id >> 4, part = id & 15;
      uint2 v = *(const uint2*)&es[o * VSTR + part * 4];
      int h = o / 48, oc = o - h * 48;
      *(uint2*)(vT + ((size_t)(b * 8 + h) * 768 + oc * 16 + c) * 256 + n0 + part * 4) = v;
    }
  }
}

// ---------------------------------------------------------------------------
// MFMA attention v15 (FINAL): h-outer ctxJ + XCD read-affinity grid.
//  * 1D grid: h = bid&7 (= XCD under round-robin), qt = (bid>>3)&15,
//    b = bid>>7.  Per XCD: 4 (b,h) groups x 671KB K/V fits 4MB L2 ->
//    FETCH 227 -> 71MB (v15-measured).
//  * Writes mapping-proof: h-outer ctxJ = block-exclusive full 128B lines.
//  * 2 blocks/CU clean-write regime (v7/v9-established); QBLK=64; 2-deep
//    QK^T pipeline; 1-deep V prefetch; in-register softmax; 96B-burst
//    staged epilogue.
// ---------------------------------------------------------------------------
#define SPBW 268
#define STGW 26

#define QK_MFMA_BLOCK(AQ0, AQ1, AQ2, AQ3, AK0, AK1, AK2, AK3)                 \
  sacc[0][0] = __builtin_amdgcn_mfma_f32_16x16x32_bf16(AQ0, AK0, sacc[0][0], 0, 0, 0); \
  sacc[1][0] = __builtin_amdgcn_mfma_f32_16x16x32_bf16(AQ1, AK0, sacc[1][0], 0, 0, 0); \
  sacc[2][0] = __builtin_amdgcn_mfma_f32_16x16x32_bf16(AQ2, AK0, sacc[2][0], 0, 0, 0); \
  sacc[3][0] = __builtin_amdgcn_mfma_f32_16x16x32_bf16(AQ3, AK0, sacc[3][0], 0, 0, 0); \
  sacc[0][1] = __builtin_amdgcn_mfma_f32_16x16x32_bf16(AQ0, AK1, sacc[0][1], 0, 0, 0); \
  sacc[1][1] = __builtin_amdgcn_mfma_f32_16x16x32_bf16(AQ1, AK1, sacc[1][1], 0, 0, 0); \
  sacc[2][1] = __builtin_amdgcn_mfma_f32_16x16x32_bf16(AQ2, AK1, sacc[2][1], 0, 0, 0); \
  sacc[3][1] = __builtin_amdgcn_mfma_f32_16x16x32_bf16(AQ3, AK1, sacc[3][1], 0, 0, 0); \
  sacc[0][2] = __builtin_amdgcn_mfma_f32_16x16x32_bf16(AQ0, AK2, sacc[0][2], 0, 0, 0); \
  sacc[1][2] = __builtin_amdgcn_mfma_f32_16x16x32_bf16(AQ1, AK2, sacc[1][2], 0, 0, 0); \
  sacc[2][2] = __builtin_amdgcn_mfma_f32_16x16x32_bf16(AQ2, AK2, sacc[2][2], 0, 0, 0); \
  sacc[3][2] = __builtin_amdgcn_mfma_f32_16x16x32_bf16(AQ3, AK2, sacc[3][2], 0, 0, 0); \
  sacc[0][3] = __builtin_amdgcn_mfma_f32_16x16x32_bf16(AQ0, AK3, sacc[0][3], 0, 0, 0); \
  sacc[1][3] = __builtin_amdgcn_mfma_f32_16x16x32_bf16(AQ1, AK3, sacc[1][3], 0, 0, 0); \
  sacc[2][3] = __builtin_amdgcn_mfma_f32_16x16x32_bf16(AQ2, AK3, sacc[2][3], 0, 0, 0); \
  sacc[3][3] = __builtin_amdgcn_mfma_f32_16x16x32_bf16(AQ3, AK3, sacc[3][3], 0, 0, 0);

__global__ __launch_bounds__(256, 2) void attn_kernel(
    const u16* __restrict__ qsel, const u16* __restrict__ ksel,
    const float* __restrict__ kbias, const float* __restrict__ daa,
    const u16* __restrict__ vT, u16* __restrict__ ctxJ) {
  // XCD read-affinity decode: h = XCD, qt innermost within (b,h)
  const int bid = blockIdx.x;
  const int h = bid & 7;
  const int qt = (bid >> 3) & 15;
  const int b = bid >> 7;
  const int g = b * 8 + h;

  const int t = threadIdx.x;
  const int w = t >> 6;
  const int lane = t & 63;
  const int m16 = lane & 15;
  const int quad = lane >> 4;

  // union: P (bf16, 64x268 = 34.3KB) then output staging (53.2KB)
  __shared__ __align__(16) u32 uni_s[13312];
  u16* spb = (u16*)uni_s;
  u32* stg = uni_s;
  __shared__ float kb[256];
  __shared__ __align__(16) float wred[64][4];
  __shared__ __align__(16) float wsum[64][4];

  const size_t bh = (size_t)g;
  const int n0 = qt * 64;
  const u16* qg = qsel + (bh * NQ + n0) * KD;
  const u16* kg = ksel + bh * NK * KD;
  const u16* vg = vT + bh * 768 * 256;

  const float ksc = -(softplusf(daa[h]) * (1.f / 48.f));
  kb[t] = ksc * kbias[bh * NK + t];
  __syncthreads();
  float kbr[4];
#pragma unroll
  for (int nt = 0; nt < 4; nt++) kbr[nt] = kb[w * 64 + nt * 16 + m16];

  f32x4 sacc[4][4];
#pragma unroll
  for (int mt = 0; mt < 4; mt++)
#pragma unroll
    for (int nt = 0; nt < 4; nt++) sacc[mt][nt] = (f32x4)0.f;

  // ---- QK^T: 17 K-steps, 2-deep software pipeline ----
  const u16* qp0 = qg + (size_t)m16 * KD + quad * 8;
  const u16* qp1 = qg + (size_t)(16 + m16) * KD + quad * 8;
  const u16* qp2 = qg + (size_t)(32 + m16) * KD + quad * 8;
  const u16* qp3 = qg + (size_t)(48 + m16) * KD + quad * 8;
  const u16* kp = kg + (size_t)(w * 64 + m16) * KD + quad * 8;
  bf16x8 cq0 = *(const bf16x8*)qp0;
  bf16x8 cq1 = *(const bf16x8*)qp1;
  bf16x8 cq2 = *(const bf16x8*)qp2;
  bf16x8 cq3 = *(const bf16x8*)qp3;
  bf16x8 ck0 = *(const bf16x8*)(kp);
  bf16x8 ck1 = *(const bf16x8*)(kp + 16 * KD);
  bf16x8 ck2 = *(const bf16x8*)(kp + 32 * KD);
  bf16x8 ck3 = *(const bf16x8*)(kp + 48 * KD);
  bf16x8 dq0 = *(const bf16x8*)(qp0 + 32);
  bf16x8 dq1 = *(const bf16x8*)(qp1 + 32);
  bf16x8 dq2 = *(const bf16x8*)(qp2 + 32);
  bf16x8 dq3 = *(const bf16x8*)(qp3 + 32);
  bf16x8 dk0 = *(const bf16x8*)(kp + 32);
  bf16x8 dk1 = *(const bf16x8*)(kp + 16 * KD + 32);
  bf16x8 dk2 = *(const bf16x8*)(kp + 32 * KD + 32);
  bf16x8 dk3 = *(const bf16x8*)(kp + 48 * KD + 32);
  for (int i = 0; i < 7; i++) {
    const int oA = (2 * i + 2) * 32;
    bf16x8 nq0 = *(const bf16x8*)(qp0 + oA);
    bf16x8 nq1 = *(const bf16x8*)(qp1 + oA);
    bf16x8 nq2 = *(const bf16x8*)(qp2 + oA);
    bf16x8 nq3 = *(const bf16x8*)(qp3 + oA);
    bf16x8 nk0 = *(const bf16x8*)(kp + oA);
    bf16x8 nk1 = *(const bf16x8*)(kp + 16 * KD + oA);
    bf16x8 nk2 = *(const bf16x8*)(kp + 32 * KD + oA);
    bf16x8 nk3 = *(const bf16x8*)(kp + 48 * KD + oA);
    const int oB = (2 * i + 3) * 32;
    bf16x8 mq0 = *(const bf16x8*)(qp0 + oB);
    bf16x8 mq1 = *(const bf16x8*)(qp1 + oB);
    bf16x8 mq2 = *(const bf16x8*)(qp2 + oB);
    bf16x8 mq3 = *(const bf16x8*)(qp3 + oB);
    bf16x8 mk0 = *(const bf16x8*)(kp + oB);
    bf16x8 mk1 = *(const bf16x8*)(kp + 16 * KD + oB);
    bf16x8 mk2 = *(const bf16x8*)(kp + 32 * KD + oB);
    bf16x8 mk3 = *(const bf16x8*)(kp + 48 * KD + oB);
    QK_MFMA_BLOCK(cq0, cq1, cq2, cq3, ck0, ck1, ck2, ck3)
    QK_MFMA_BLOCK(dq0, dq1, dq2, dq3, dk0, dk1, dk2, dk3)
    cq0 = nq0; cq1 = nq1; cq2 = nq2; cq3 = nq3;
    ck0 = nk0; ck1 = nk1; ck2 = nk2; ck3 = nk3;
    dq0 = mq0; dq1 = mq1; dq2 = mq2; dq3 = mq3;
    dk0 = mk0; dk1 = mk1; dk2 = mk2; dk3 = mk3;
  }
  {
    const int oT = 16 * 32;
    bf16x8 nq0 = *(const bf16x8*)(qp0 + oT);
    bf16x8 nq1 = *(const bf16x8*)(qp1 + oT);
    bf16x8 nq2 = *(const bf16x8*)(qp2 + oT);
    bf16x8 nq3 = *(const bf16x8*)(qp3 + oT);
    bf16x8 nk0 = *(const bf16x8*)(kp + oT);
    bf16x8 nk1 = *(const bf16x8*)(kp + 16 * KD + oT);
    bf16x8 nk2 = *(const bf16x8*)(kp + 32 * KD + oT);
    bf16x8 nk3 = *(const bf16x8*)(kp + 48 * KD + oT);
    QK_MFMA_BLOCK(cq0, cq1, cq2, cq3, ck0, ck1, ck2, ck3)
    QK_MFMA_BLOCK(dq0, dq1, dq2, dq3, dk0, dk1, dk2, dk3)
    QK_MFMA_BLOCK(nq0, nq1, nq2, nq3, nk0, nk1, nk2, nk3)
  }

  // ---- softmax, in-register ----
#pragma unroll
  for (int mt = 0; mt < 4; mt++)
#pragma unroll
    for (int rr = 0; rr < 4; rr++) {
      float a0 = sacc[mt][0][rr] + kbr[0];
      float a1 = sacc[mt][1][rr] + kbr[1];
      float a2 = sacc[mt][2][rr] + kbr[2];
      float a3 = sacc[mt][3][rr] + kbr[3];
      sacc[mt][0][rr] = a0; sacc[mt][1][rr] = a1;
      sacc[mt][2][rr] = a2; sacc[mt][3][rr] = a3;
      float m = fmaxf(fmaxf(a0, a1), fmaxf(a2, a3));
#pragma unroll
      for (int off = 1; off < 16; off <<= 1)
        m = fmaxf(m, __shfl_xor(m, off));
      if (m16 == mt * 4 + rr) wred[mt * 16 + quad * 4 + rr][w] = m;
    }
  __syncthreads();
#pragma unroll
  for (int mt = 0; mt < 4; mt++)
#pragma unroll
    for (int rr = 0; rr < 4; rr++) {
      const int row = mt * 16 + quad * 4 + rr;
      float4 m4 = *(const float4*)wred[row];
      const float gm = fmaxf(fmaxf(m4.x, m4.y), fmaxf(m4.z, m4.w));
      float s = 0.f;
#pragma unroll
      for (int nt = 0; nt < 4; nt++) {
        float e = __expf(sacc[mt][nt][rr] - gm);
        s += e;
        spb[row * SPBW + w * 64 + nt * 16 + m16] = f2bf(e);
      }
#pragma unroll
      for (int off = 1; off < 16; off <<= 1)
        s += __shfl_xor(s, off);
      if (m16 == mt * 4 + rr) wsum[row][w] = s;
    }
  __syncthreads();

  // ---- PV: D[m=q-row][n=d]; 1-deep V prefetch ----
  f32x4 oacc[4][12];
#pragma unroll
  for (int mt = 0; mt < 4; mt++)
#pragma unroll
    for (int nt = 0; nt < 12; nt++) oacc[mt][nt] = (f32x4)0.f;

  const u16* vp = vg + (size_t)(w * 192 + m16) * 256 + quad * 8;
  bf16x8 vc[12];
#pragma unroll
  for (int nt = 0; nt < 12; nt++)
    vc[nt] = *(const bf16x8*)(vp + (size_t)nt * 16 * 256);
#pragma unroll
  for (int ks = 0; ks < 8; ks++) {
    bf16x8 vn[12];
    if (ks < 7) {
#pragma unroll
      for (int nt = 0; nt < 12; nt++)
        vn[nt] = *(const bf16x8*)(vp + (size_t)nt * 16 * 256 + (ks + 1) * 32);
    }
    bf16x8 pa0 = *(const bf16x8*)(&spb[(size_t)m16 * SPBW + ks * 32 + quad * 8]);
    bf16x8 pa1 = *(const bf16x8*)(&spb[(size_t)(16 + m16) * SPBW + ks * 32 + quad * 8]);
    bf16x8 pa2 = *(const bf16x8*)(&spb[(size_t)(32 + m16) * SPBW + ks * 32 + quad * 8]);
    bf16x8 pa3 = *(const bf16x8*)(&spb[(size_t)(48 + m16) * SPBW + ks * 32 + quad * 8]);
#pragma unroll
    for (int nt = 0; nt < 12; nt++) {
      oacc[0][nt] = __builtin_amdgcn_mfma_f32_16x16x32_bf16(pa0, vc[nt], oacc[0][nt], 0, 0, 0);
      oacc[1][nt] = __builtin_amdgcn_mfma_f32_16x16x32_bf16(pa1, vc[nt], oacc[1][nt], 0, 0, 0);
      oacc[2][nt] = __builtin_amdgcn_mfma_f32_16x16x32_bf16(pa2, vc[nt], oacc[2][nt], 0, 0, 0);
      oacc[3][nt] = __builtin_amdgcn_mfma_f32_16x16x32_bf16(pa3, vc[nt], oacc[3][nt], 0, 0, 0);
    }
    if (ks < 7) {
#pragma unroll
      for (int nt = 0; nt < 12; nt++) vc[nt] = vn[nt];
    }
  }

  // ---- staged epilogue: 2 chunks of 8 c; full 96B runs, h-OUTER ctxJ ----
  const size_t rowbase = (size_t)b * NQ + n0;
#pragma unroll
  for (int ch2 = 0; ch2 < 2; ch2++) {
    __syncthreads();
    if ((m16 >> 3) == ch2) {
      const int c8 = m16 & 7;
#pragma unroll
      for (int mt = 0; mt < 4; mt++)
#pragma unroll
        for (int rr = 0; rr < 4; rr++) {
          const int row = mt * 16 + quad * 4 + rr;
          float4 s4 = *(const float4*)wsum[row];
          const float iv = 1.f / (s4.x + s4.y + s4.z + s4.w);
          u32* dp = stg + (row * 8 + c8) * STGW + w * 6;
#pragma unroll
          for (int j = 0; j < 6; j++) {
            u32 lo = f2bf(oacc[mt][2 * j][rr] * iv);
            u32 hi = f2bf(oacc[mt][2 * j + 1][rr] * iv);
            dp[j] = lo | (hi << 16);
          }
        }
    }
    __syncthreads();
    for (int ch = t; ch < 512; ch += 256) {
      const int prow = ch >> 3, pc8 = ch & 7;
      const u32* sp2 = stg + (prow * 8 + pc8) * STGW;
      u16* dst = ctxJ +
          (((size_t)(h * 16 + ch2 * 8 + pc8)) * 8192 + rowbase + prow) * 48;
#pragma unroll
      for (int j6 = 0; j6 < 6; j6++) {
        uint2 a = *(const uint2*)(sp2 + j6 * 4);
        uint2 bb2 = *(const uint2*)(sp2 + j6 * 4 + 2);
        uint4 v4v = {a.x, a.y, bb2.x, bb2.y};
        *(uint4*)(dst + j6 * 8) = v4v;
      }
    }
  }
}

// ---------------------------------------------------------------------------
// out_kernel v6: 16 rows/block, grid 512, 2 blocks/CU.  ctxJ h-outer
// [h*16+c][row][48] -> per-fragment decode h=k/48 (48%8==0 so each 8-elem
// fragment stays inside one h-slice; harness-verified).
// ---------------------------------------------------------------------------
#define ESTR2 785
__global__ __launch_bounds__(1024) void out_kernel(
    const u16* __restrict__ ctxJ, const u16* __restrict__ WoB,
    const float* __restrict__ bo, const float* __restrict__ hidden,
    float* __restrict__ out) {
  __shared__ __align__(16) float es[16 * ESTR2];  // 50.2 KB
  const int t = threadIdx.x;
  const int c = __builtin_amdgcn_readfirstlane(t >> 6);
  const int lane = t & 63;
  const int m16 = lane & 15, quad = lane >> 4;
  const int r0 = blockIdx.x * 16;
  const int g = grade_of(c);
  const u16* wb = WoB + (size_t)g * 48 * 384;
  const int q8 = quad * 8;

  f32x4 acc[3];
#pragma unroll
  for (int nt = 0; nt < 3; nt++) acc[nt] = (f32x4)0.f;
#pragma unroll
  for (int ks = 0; ks < 12; ks++) {
    const int k0 = ks * 32 + q8;
    const int hh = k0 / 48;
    const int oc = k0 - hh * 48;
    bf16x8 af = *(const bf16x8*)(ctxJ +
        (((size_t)(hh * 16 + c)) * 8192 + r0 + m16) * 48 + oc);
#pragma unroll
    for (int nt = 0; nt < 3; nt++) {
      bf16x8 bf = *(const bf16x8*)(wb + (size_t)(nt * 16 + m16) * 384 + ks * 32 + q8);
      acc[nt] = __builtin_amdgcn_mfma_f32_16x16x32_bf16(af, bf, acc[nt], 0, 0, 0);
    }
  }
  __syncthreads();
#pragma unroll
  for (int nt = 0; nt < 3; nt++)
#pragma unroll
    for (int rr = 0; rr < 4; rr++)
      es[(quad * 4 + rr) * ESTR2 + c * 49 + nt * 16 + m16] = acc[nt][rr];
  __syncthreads();
#pragma unroll
  for (int k = 0; k < 3; k++) {
    int m4 = t + 1024 * k;
    int r = m4 / 192;
    int col0 = (m4 - r * 192) * 4;
    int o = col0 >> 4, cb = col0 & 15;
    const float* er = &es[r * ESTR2 + o];
    float4 v;
    v.x = er[(cb + 0) * 49];
    v.y = er[(cb + 1) * 49];
    v.z = er[(cb + 2) * 49];
    v.w = er[(cb + 3) * 49];
    if (cb == 0) v.x += bo[o];
    size_t gidx = (size_t)(r0 + r) * 768 + col0;
    const float4 hv = *(const float4*)&hidden[gidx];
    v.x += hv.x; v.y += hv.y; v.z += hv.z; v.w += hv.w;
    *(float4*)&out[gidx] = v;
  }
}

// ---------------------------------------------------------------------------
extern "C" void kernel_launch(void* const* d_in, const int* in_sizes, int n_in,
                              void* d_out, int out_size, void* d_ws, size_t ws_size,
                              hipStream_t stream) {
  const float* hidden = (const float*)d_in[0];
  const float* vis = (const float*)d_in[1];
  const float* lnw = (const float*)d_in[2];
  const float* Wq = (const float*)d_in[3];
  const float* bq = (const float*)d_in[4];
  const float* Wkv = (const float*)d_in[5];
  const float* bkv = (const float*)d_in[6];
  const float* Wo = (const float*)d_in[7];
  const float* bo = (const float*)d_in[8];
  const float* daa = (const float*)d_in[9];
  float* out = (float*)d_out;

  char* ws = (char*)d_ws;
  size_t off = 0;
  auto carve = [&](size_t bytes) -> void* {
    void* p = ws + off;
    off += (bytes + 255) & ~(size_t)255;
    return p;
  };
  u16* WqB = (u16*)carve((size_t)5 * 384 * 64 * 2);
  u16* WkvB = (u16*)carve((size_t)5 * 768 * 64 * 2);
  u16* WoB = (u16*)carve((size_t)5 * 48 * 384 * 2);
  u16* qsel = (u16*)carve((size_t)BB * HH * NQ * KD * 2);
  u16* ksel = (u16*)carve((size_t)BB * HH * NK * KD * 2);
  u16* vT = (u16*)carve((size_t)BB * HH * 768 * 256 * 2);
  float* kbias = (float*)carve((size_t)BB * HH * NK * 4);
  // union: [xq | xv] consumed by qkv, then ctxJ ([h*16+c][row][48]) overwrites
  char* uni = (char*)carve((size_t)16 * 384 * 8192 * 2);
  u16* ctxJ = (u16*)uni;
  u16* xq = (u16*)uni;                                      // 16 MB
  u16* xv = (u16*)(uni + (size_t)16 * 8192 * 64 * 2);       // 4 MB

  wB_kernel<<<1800, 256, 0, stream>>>(Wq, Wkv, Wo, WqB, WkvB, WoB, kbias);
  xJ_kernel<<<160, 256, 0, stream>>>(hidden, vis, xq, xv, lnw);
  qkv_mfma<<<2272, 256, 0, stream>>>(xq, xv, WqB, WkvB, bq, bkv, daa,
                                     qsel, ksel, vT, kbias);
  attn_kernel<<<1024, 256, 0, stream>>>(qsel, ksel, kbias, daa, vT, ctxJ);
  out_kernel<<<512, 1024, 0, stream>>>(ctxJ, WoB, bo, hidden, out);
}